// Round 15
// baseline (128.441 us; speedup 1.0000x reference)
//
#include <hip/hip_runtime.h>

#define S_LEN 2048
#define NH 16
#define HD 64
#define DM 1024
#define MTOT 4096

// q pre-scale: 1/sqrt(64) * log2(e), so attn softmax is exp2(q.k)
#define QSCALE 0.18033688011112042f

typedef short bf16x8 __attribute__((ext_vector_type(8)));
typedef float f32x4 __attribute__((ext_vector_type(4)));
typedef unsigned short u16x8 __attribute__((ext_vector_type(8)));
typedef int i32x4 __attribute__((ext_vector_type(4)));

__device__ __forceinline__ unsigned short f2bf(float f) {
  unsigned int u = __builtin_bit_cast(unsigned int, f);
  u += 0x7fffu + ((u >> 16) & 1u);
  return (unsigned short)(u >> 16);
}

__device__ __forceinline__ unsigned int cvt_pk_bf16(float lo, float hi) {
  unsigned int r;
  asm("v_cvt_pk_bf16_f32 %0, %1, %2" : "=v"(r) : "v"(lo), "v"(hi));
  return r;
}

__device__ __forceinline__ void async_copy16(const void* g, void* l) {
  __builtin_amdgcn_global_load_lds(
      (const __attribute__((address_space(1))) unsigned int*)g,
      (__attribute__((address_space(3))) unsigned int*)l, 16, 0, 0);
}

// ---------------- fp32 -> bf16 convert ----------------
__global__ void cvt_bf16_kernel(const float* __restrict__ src,
                                unsigned short* __restrict__ dst, int n) {
  int i = (blockIdx.x * 256 + threadIdx.x) * 8;
  if (i >= n) return;
  const float4* s = (const float4*)(src + i);
  float4 v0 = s[0], v1 = s[1];
  u16x8 o;
  o[0] = f2bf(v0.x); o[1] = f2bf(v0.y); o[2] = f2bf(v0.z); o[3] = f2bf(v0.w);
  o[4] = f2bf(v1.x); o[5] = f2bf(v1.y); o[6] = f2bf(v1.z); o[7] = f2bf(v1.w);
  *(u16x8*)(dst + i) = o;
}

// 4 weight matrices in one launch
__global__ void cvt_w_kernel(const float* __restrict__ w0, const float* __restrict__ w1,
                             const float* __restrict__ w2, const float* __restrict__ w3,
                             unsigned short* __restrict__ dst) {
  int z = blockIdx.y;
  const float* src = (z == 0) ? w0 : (z == 1) ? w1 : (z == 2) ? w2 : w3;
  int i = (blockIdx.x * 256 + threadIdx.x) * 8;
  const float4* s = (const float4*)(src + i);
  float4 v0 = s[0], v1 = s[1];
  u16x8 o;
  o[0] = f2bf(v0.x); o[1] = f2bf(v0.y); o[2] = f2bf(v0.z); o[3] = f2bf(v0.w);
  o[4] = f2bf(v1.x); o[5] = f2bf(v1.y); o[6] = f2bf(v1.z); o[7] = f2bf(v1.w);
  *(u16x8*)(dst + (size_t)z * DM * DM + i) = o;
}

// ---------------- RoPE cos/sin table ----------------
__global__ void sincos_tab_kernel(const int* __restrict__ pos, float2* __restrict__ tab) {
  int idx = blockIdx.x * 256 + threadIdx.x;  // 0 .. 65535
  int s = idx >> 5, i = idx & 31;
  float fr = expf(-(float)i * 0.28782313662425574f);  // ln(10000)/32
  float ang = (float)pos[s] * fr;
  float sn, cs;
  sincosf(ang, &sn, &cs);
  tab[idx] = make_float2(cs, sn);
}

// ---------------- shared GEMM core: C = A(MxK) @ Bt(NxK)^T, 128x128 tile, BK=64 ----------------
// Double-buffered LDS (R9-measured best): stage(next) issued BEFORE compute(cur);
// single vmcnt(0)+barrier per K-step. XOR-swizzled layout (T2): LDS[r][j] = SRC[r][j^(r&7)],
// 16B granules, pre-swizzled source (rule #21: linear dest + inverse-swz source + swz read).
__device__ __forceinline__ void gemm_core(const unsigned short* __restrict__ A,
                                          const unsigned short* __restrict__ Bt,
                                          int m0, int n0, int K,
                                          char* a_lds, char* b_lds,  // each 2 x 16KB
                                          f32x4 (&acc)[4][4]) {
  const int tid = threadIdx.x;
  const int w = tid >> 6, l = tid & 63;
  const int wr = w >> 1, wc = w & 1;
  const int c = l & 15, g = l >> 4;

  const size_t rs = (size_t)K * 2;  // row stride bytes
  const int lr = l >> 3;
  const int jsw = ((l & 7) ^ lr) << 4;  // pre-swizzled source granule
  const char* srcA = (const char*)A + ((size_t)m0 + w * 8 + lr) * rs + jsw;
  const char* srcB = (const char*)Bt + ((size_t)n0 + w * 8 + lr) * rs + jsw;
  char* dstA = a_lds + w * 1024 + l * 16;
  char* dstB = b_lds + w * 1024 + l * 16;
  const int csw = (c & 7) << 4;
  const int nsteps = K / 64;

  auto stage = [&](int buf, int kt) {
    const int off = buf * 16384;
#pragma unroll
    for (int i = 0; i < 4; ++i) {
      async_copy16(srcA + (size_t)i * 32 * rs + kt * 128, dstA + off + i * 4096);
      async_copy16(srcB + (size_t)i * 32 * rs + kt * 128, dstB + off + i * 4096);
    }
  };

  stage(0, 0);
  asm volatile("s_waitcnt vmcnt(0)" ::: "memory");
  __syncthreads();
  int cur = 0;

  for (int kt = 0; kt < nsteps; ++kt) {
    if (kt + 1 < nsteps) stage(cur ^ 1, kt + 1);  // issue next tile early
    const char* al = a_lds + cur * 16384;
    const char* bl = b_lds + cur * 16384;
    __builtin_amdgcn_s_setprio(1);
#pragma unroll
    for (int kk = 0; kk < 2; ++kk) {
      bf16x8 af[4], bfv[4];
#pragma unroll
      for (int mi = 0; mi < 4; ++mi)
        af[mi] = *(const bf16x8*)(al + (wr * 64 + mi * 16 + c) * 128 + ((kk * 64 + g * 16) ^ csw));
#pragma unroll
      for (int ni = 0; ni < 4; ++ni)
        bfv[ni] = *(const bf16x8*)(bl + (wc * 64 + ni * 16 + c) * 128 + ((kk * 64 + g * 16) ^ csw));
#pragma unroll
      for (int mi = 0; mi < 4; ++mi)
#pragma unroll
        for (int ni = 0; ni < 4; ++ni)
          acc[mi][ni] = __builtin_amdgcn_mfma_f32_16x16x32_bf16(af[mi], bfv[ni], acc[mi][ni], 0, 0, 0);
    }
    __builtin_amdgcn_s_setprio(0);
    asm volatile("s_waitcnt vmcnt(0)" ::: "memory");  // next tile landed
    __syncthreads();                                  // all waves done with cur
    cur ^= 1;
  }
}

// ---------------- QKV projection + fused RoPE: q,k -> [b,h,s,d]; v -> [b,h,d,s] ----------------
__global__ __launch_bounds__(256)
void gemm_qkv_kernel(const unsigned short* __restrict__ X,
                     const unsigned short* __restrict__ Wq,
                     const unsigned short* __restrict__ Wk,
                     const unsigned short* __restrict__ Wv,
                     const float2* __restrict__ tab,
                     unsigned short* __restrict__ Qb,
                     unsigned short* __restrict__ Kb,
                     unsigned short* __restrict__ Vt) {
  __shared__ char a_lds[2 * 16384];
  __shared__ char b_lds[2 * 16384];
  const int z = blockIdx.z;
  const unsigned short* Bt = (z == 0) ? Wq : (z == 1) ? Wk : Wv;
  const int m0 = blockIdx.x * 128, n0 = blockIdx.y * 128;

  f32x4 acc[4][4] = {};
  gemm_core(X, Bt, m0, n0, DM, a_lds, b_lds, acc);

  const int tid = threadIdx.x;
  const int w = tid >> 6, l = tid & 63;
  const int wr = w >> 1, wc = w & 1;
  const int c = l & 15, g = l >> 4;

  if (z == 2) {
#pragma unroll
    for (int mi = 0; mi < 4; ++mi)
#pragma unroll
      for (int ni = 0; ni < 4; ++ni)
#pragma unroll
        for (int r = 0; r < 4; ++r) {
          int row = m0 + wr * 64 + mi * 16 + 4 * g + r;  // token
          int col = n0 + wc * 64 + ni * 16 + c;          // feature
          int b = row >> 11, s = row & 2047;
          int h = col >> 6, d = col & 63;
          Vt[((size_t)(b * NH + h) * HD + d) * S_LEN + s] = f2bf(acc[mi][ni][r]);
        }
  } else {
    unsigned short* QK = z ? Kb : Qb;
    const float oscale = z ? 1.0f : QSCALE;
#pragma unroll
    for (int mi = 0; mi < 4; ++mi)
#pragma unroll
      for (int ni = 0; ni < 4; ++ni) {
        int col = n0 + wc * 64 + ni * 16 + c;
        int fi = (col >> 1) & 31;
        float sgn = (col & 1) ? 1.0f : -1.0f;
#pragma unroll
        for (int r = 0; r < 4; ++r) {
          int row = m0 + wr * 64 + mi * 16 + 4 * g + r;
          int b = row >> 11, s = row & 2047;
          float v = acc[mi][ni][r];
          float p = __shfl_xor(v, 1);
          float2 csn = tab[(s << 5) | fi];
          float vr = (v * csn.x + sgn * p * csn.y) * oscale;
          int h = col >> 6, d = col & 63;
          QK[((size_t)(b * NH + h) * S_LEN + s) * HD + d] = f2bf(vr);
        }
      }
  }
}

// ---------------- output projection: fp32 out ----------------
__global__ __launch_bounds__(256)
void gemm_out_kernel(const unsigned short* __restrict__ A,
                     const unsigned short* __restrict__ Wo,
                     float* __restrict__ out) {
  __shared__ char a_lds[2 * 16384];
  __shared__ char b_lds[2 * 16384];
  const int m0 = blockIdx.x * 128, n0 = blockIdx.y * 128;
  f32x4 acc[4][4] = {};
  gemm_core(A, Wo, m0, n0, DM, a_lds, b_lds, acc);

  const int tid = threadIdx.x;
  const int w = tid >> 6, l = tid & 63;
  const int wr = w >> 1, wc = w & 1;
  const int c = l & 15, g = l >> 4;
#pragma unroll
  for (int mi = 0; mi < 4; ++mi)
#pragma unroll
    for (int ni = 0; ni < 4; ++ni)
#pragma unroll
      for (int r = 0; r < 4; ++r) {
        int row = m0 + wr * 64 + mi * 16 + 4 * g + r;
        int col = n0 + wc * 64 + ni * 16 + c;
        out[(size_t)row * DM + col] = acc[mi][ni][r];
      }
}

// ---------------- causal flash attention: concatenated q-tile pair, uniform 33 steps ----------------
// Block = (bh, j): runs q-tile qa=j over kv 0..qa, THEN q-tile qb=31-j over kv 0..qb,
// in ONE continuous staging pipeline -> exactly 33 steps per block, no tail decay.
// Swapped QK^T (S^T in regs), register-P via cvt_pk+shfl, no P-LDS.
__global__ __launch_bounds__(256, 2)
void attn_kernel(const unsigned short* __restrict__ Q,
                 const unsigned short* __restrict__ Kb,
                 const unsigned short* __restrict__ Vt,
                 unsigned short* __restrict__ Ob) {
  __shared__ char kbuf[2][8192];
  __shared__ char vbuf[2][8192];
  const int tid = threadIdx.x;
  const int w = tid >> 6, l = tid & 63;
  const int g = l >> 4, c = l & 15;

  const unsigned int id = blockIdx.x;
  const int bh = id & 31;
  const int j = id >> 5;        // 0..15
  const int qa = j, qb = 31 - j;

  const size_t base = (size_t)bh * (S_LEN * HD);
  const char* Kc = (const char*)(Kb + base);
  const char* Vc = (const char*)(Vt + base);

  const int lr = l >> 3;
  const int jsw = ((l & 7) << 4) ^ (lr << 4);
  const int r0 = w * 8 + lr;
  const int r1 = (4 + w) * 8 + lr;
  const char* ksrc0 = Kc + r0 * 128 + jsw;
  const char* ksrc1 = Kc + r1 * 128 + jsw;
  const char* vsrc0 = Vc + r0 * 4096 + jsw;
  const char* vsrc1 = Vc + r1 * 4096 + jsw;

  const unsigned short* Qrow = Q + base + (size_t)(w * 16 + c) * HD + g * 8;
  const int b = bh >> 4, h = bh & 15;
  unsigned short* Obase = Ob + ((size_t)b * S_LEN + w * 16 + c) * DM + h * HD + 4 * g;

  // phase state: start with q-tile qa
  int q0 = qa * 64;
  int qcur = qa;
  bf16x8 qf0, qf1;
  {
    const unsigned short* qp = Qrow + (size_t)q0 * HD;
    qf0 = *(const bf16x8*)qp;
    qf1 = *(const bf16x8*)(qp + 32);
  }
  f32x4 oacc[4] = {};
  float rsum = 0.f;
  const int csw = (c & 7) << 4;
  const int srcA = (l & 15) | ((l & 16) << 1);
  const int srcB = srcA + 16;
  const bool hi = (l >= 32);

  auto stage = [&](int buf, int t) {
    char* kd = &kbuf[buf][w * 1024 + l * 16];
    char* vd = &vbuf[buf][w * 1024 + l * 16];
    size_t ko = (size_t)t * 8192;
    size_t vo = (size_t)t * 128;
    async_copy16(ksrc0 + ko, kd);
    async_copy16(ksrc1 + ko, kd + 4096);
    async_copy16(vsrc0 + vo, vd);
    async_copy16(vsrc1 + vo, vd + 4096);
  };

  stage(0, 0);
  asm volatile("s_waitcnt vmcnt(0)" ::: "memory");
  __syncthreads();
  int cur = 0;
  int t = 0;

  for (int s = 0; s < 33; ++s) {
    // stage next step's tile: t+1 within phase, or 0 at phase switch (pipeline never drains)
    if (s < 32) stage(cur ^ 1, (t == qcur) ? 0 : t + 1);
    const char* kl = kbuf[cur];
    const char* vl = vbuf[cur];
    const int kv0 = t * 64;
    const bool last = (t == qcur);  // diag tile of current phase

    f32x4 sc[4] = {};
    __builtin_amdgcn_s_setprio(1);
#pragma unroll
    for (int nt = 0; nt < 4; ++nt) {
      bf16x8 k0 = *(const bf16x8*)(kl + (nt * 16 + c) * 128 + ((g * 16) ^ csw));
      bf16x8 k1 = *(const bf16x8*)(kl + (nt * 16 + c) * 128 + ((64 + g * 16) ^ csw));
      sc[nt] = __builtin_amdgcn_mfma_f32_16x16x32_bf16(k0, qf0, sc[nt], 0, 0, 0);
      sc[nt] = __builtin_amdgcn_mfma_f32_16x16x32_bf16(k1, qf1, sc[nt], 0, 0, 0);
    }
    __builtin_amdgcn_s_setprio(0);

    // softmax (no running max; q pre-scaled so P = exp2(s)); S^T: kv = kv0+nt*16+4g+r, q = q0+w*16+c
    if (last) {
      const int qi = q0 + w * 16 + c;
#pragma unroll
      for (int nt = 0; nt < 4; ++nt)
#pragma unroll
        for (int r = 0; r < 4; ++r) {
          int kvi = kv0 + nt * 16 + 4 * g + r;
          sc[nt][r] = exp2f((kvi > qi) ? -1e30f : sc[nt][r]);
        }
    } else {
#pragma unroll
      for (int nt = 0; nt < 4; ++nt)
#pragma unroll
        for (int r = 0; r < 4; ++r)
          sc[nt][r] = exp2f(sc[nt][r]);
    }
    unsigned int pk[4][2];
#pragma unroll
    for (int nt = 0; nt < 4; ++nt) {
      rsum += (sc[nt][0] + sc[nt][1]) + (sc[nt][2] + sc[nt][3]);
      pk[nt][0] = cvt_pk_bf16(sc[nt][0], sc[nt][1]);
      pk[nt][1] = cvt_pk_bf16(sc[nt][2], sc[nt][3]);
    }

    __builtin_amdgcn_s_setprio(1);
#pragma unroll
    for (int ks = 0; ks < 2; ++ks) {
      int a0 = __shfl((int)pk[2 * ks][0], srcA);
      int a1 = __shfl((int)pk[2 * ks][1], srcA);
      int a2 = __shfl((int)pk[2 * ks][0], srcB);
      int a3 = __shfl((int)pk[2 * ks][1], srcB);
      int b0 = __shfl((int)pk[2 * ks + 1][0], srcA);
      int b1 = __shfl((int)pk[2 * ks + 1][1], srcA);
      int b2 = __shfl((int)pk[2 * ks + 1][0], srcB);
      int b3 = __shfl((int)pk[2 * ks + 1][1], srcB);
      i32x4 pw;
      pw[0] = hi ? b0 : a0;
      pw[1] = hi ? b1 : a1;
      pw[2] = hi ? b2 : a2;
      pw[3] = hi ? b3 : a3;
      bf16x8 pf = __builtin_bit_cast(bf16x8, pw);
#pragma unroll
      for (int nt = 0; nt < 4; ++nt) {
        bf16x8 vf = *(const bf16x8*)(vl + (nt * 16 + c) * 128 + ((ks * 64 + g * 16) ^ csw));
        oacc[nt] = __builtin_amdgcn_mfma_f32_16x16x32_bf16(vf, pf, oacc[nt], 0, 0, 0);
      }
    }
    __builtin_amdgcn_s_setprio(0);

    if (last) {
      // phase epilogue: normalize + store O^T for this q-tile, then switch to phase B
      float rs = rsum;
      rs += __shfl_xor(rs, 16);
      rs += __shfl_xor(rs, 32);
      const float inv = 1.0f / rs;
      unsigned short* dst = Obase + (size_t)q0 * DM;
#pragma unroll
      for (int nt = 0; nt < 4; ++nt) {
        unsigned int w0 = (unsigned int)f2bf(oacc[nt][0] * inv) | ((unsigned int)f2bf(oacc[nt][1] * inv) << 16);
        unsigned int w1 = (unsigned int)f2bf(oacc[nt][2] * inv) | ((unsigned int)f2bf(oacc[nt][3] * inv) << 16);
        uint2 pr;
        pr.x = w0;
        pr.y = w1;
        *(uint2*)(dst + nt * 16) = pr;
        oacc[nt] = f32x4{0.f, 0.f, 0.f, 0.f};
      }
      rsum = 0.f;
      if (s < 32) {
        q0 = qb * 64;
        qcur = qb;
        t = 0;
        const unsigned short* qp = Qrow + (size_t)q0 * HD;
        qf0 = *(const bf16x8*)qp;
        qf1 = *(const bf16x8*)(qp + 32);
      }
    } else {
      ++t;
    }

    asm volatile("s_waitcnt vmcnt(0)" ::: "memory");  // next tile landed (also drains O stores)
    __syncthreads();                                  // all waves done with cur
    cur ^= 1;
  }
}

extern "C" void kernel_launch(void* const* d_in, const int* in_sizes, int n_in,
                              void* d_out, int out_size, void* d_ws, size_t ws_size,
                              hipStream_t stream) {
  const float* x = (const float*)d_in[0];
  const int* tpos = (const int*)d_in[1];
  const float* wq = (const float*)d_in[2];
  const float* wk = (const float*)d_in[3];
  const float* wv = (const float*)d_in[4];
  const float* wo = (const float*)d_in[5];
  float* out = (float*)d_out;

  char* ws = (char*)d_ws;
  unsigned short* xb = (unsigned short*)(ws);                          // 4096x1024 bf16
  unsigned short* wqb = (unsigned short*)(ws + 8388608);               // 4x 1024x1024
  unsigned short* wkb = wqb + DM * DM;
  unsigned short* wvb = wqb + 2 * DM * DM;
  unsigned short* wob = wqb + 3 * DM * DM;
  unsigned short* qb = (unsigned short*)(ws + 16777216);               // [b,h,s,d] pre-scaled
  unsigned short* kb = (unsigned short*)(ws + 16777216 + 8388608);     // [b,h,s,d]
  unsigned short* vt = (unsigned short*)(ws + 16777216 + 2 * 8388608); // [b,h,d,s]
  unsigned short* ab = (unsigned short*)(ws + 16777216 + 3 * 8388608); // [t, h*d]
  float2* tab = (float2*)(ws + 50331648);                              // [2048][32] cos/sin

  cvt_bf16_kernel<<<2048, 256, 0, stream>>>(x, xb, MTOT * DM);
  cvt_w_kernel<<<dim3(512, 4), 256, 0, stream>>>(wq, wk, wv, wo, wqb);
  sincos_tab_kernel<<<256, 256, 0, stream>>>(tpos, tab);

  gemm_qkv_kernel<<<dim3(32, 8, 3), 256, 0, stream>>>(xb, wqb, wkb, wvb, tab, qb, kb, vt);
  attn_kernel<<<512, 256, 0, stream>>>(qb, kb, vt, ab);
  gemm_out_kernel<<<dim3(32, 8), 256, 0, stream>>>(ab, wob, out);
}

// Round 16
// 123.289 us; speedup vs baseline: 1.0418x; 1.0418x over previous
//
#include <hip/hip_runtime.h>

#define S_LEN 2048
#define NH 16
#define HD 64
#define DM 1024
#define MTOT 4096

// q pre-scale: 1/sqrt(64) * log2(e), so attn softmax is exp2(q.k)
#define QSCALE 0.18033688011112042f

typedef short bf16x8 __attribute__((ext_vector_type(8)));
typedef float f32x4 __attribute__((ext_vector_type(4)));
typedef unsigned short u16x8 __attribute__((ext_vector_type(8)));
typedef int i32x4 __attribute__((ext_vector_type(4)));

__device__ __forceinline__ unsigned short f2bf(float f) {
  unsigned int u = __builtin_bit_cast(unsigned int, f);
  u += 0x7fffu + ((u >> 16) & 1u);
  return (unsigned short)(u >> 16);
}

__device__ __forceinline__ unsigned int cvt_pk_bf16(float lo, float hi) {
  unsigned int r;
  asm("v_cvt_pk_bf16_f32 %0, %1, %2" : "=v"(r) : "v"(lo), "v"(hi));
  return r;
}

__device__ __forceinline__ void async_copy16(const void* g, void* l) {
  __builtin_amdgcn_global_load_lds(
      (const __attribute__((address_space(1))) unsigned int*)g,
      (__attribute__((address_space(3))) unsigned int*)l, 16, 0, 0);
}

// ---------------- fp32 -> bf16 convert ----------------
__global__ void cvt_bf16_kernel(const float* __restrict__ src,
                                unsigned short* __restrict__ dst, int n) {
  int i = (blockIdx.x * 256 + threadIdx.x) * 8;
  if (i >= n) return;
  const float4* s = (const float4*)(src + i);
  float4 v0 = s[0], v1 = s[1];
  u16x8 o;
  o[0] = f2bf(v0.x); o[1] = f2bf(v0.y); o[2] = f2bf(v0.z); o[3] = f2bf(v0.w);
  o[4] = f2bf(v1.x); o[5] = f2bf(v1.y); o[6] = f2bf(v1.z); o[7] = f2bf(v1.w);
  *(u16x8*)(dst + i) = o;
}

// 4 weight matrices in one launch
__global__ void cvt_w_kernel(const float* __restrict__ w0, const float* __restrict__ w1,
                             const float* __restrict__ w2, const float* __restrict__ w3,
                             unsigned short* __restrict__ dst) {
  int z = blockIdx.y;
  const float* src = (z == 0) ? w0 : (z == 1) ? w1 : (z == 2) ? w2 : w3;
  int i = (blockIdx.x * 256 + threadIdx.x) * 8;
  const float4* s = (const float4*)(src + i);
  float4 v0 = s[0], v1 = s[1];
  u16x8 o;
  o[0] = f2bf(v0.x); o[1] = f2bf(v0.y); o[2] = f2bf(v0.z); o[3] = f2bf(v0.w);
  o[4] = f2bf(v1.x); o[5] = f2bf(v1.y); o[6] = f2bf(v1.z); o[7] = f2bf(v1.w);
  *(u16x8*)(dst + (size_t)z * DM * DM + i) = o;
}

// ---------------- RoPE cos/sin table ----------------
__global__ void sincos_tab_kernel(const int* __restrict__ pos, float2* __restrict__ tab) {
  int idx = blockIdx.x * 256 + threadIdx.x;  // 0 .. 65535
  int s = idx >> 5, i = idx & 31;
  float fr = expf(-(float)i * 0.28782313662425574f);  // ln(10000)/32
  float ang = (float)pos[s] * fr;
  float sn, cs;
  sincosf(ang, &sn, &cs);
  tab[idx] = make_float2(cs, sn);
}

// ---------------- shared GEMM core: C = A(MxK) @ Bt(NxK)^T, 128x128 tile, BK=64 ----------------
__device__ __forceinline__ void gemm_core(const unsigned short* __restrict__ A,
                                          const unsigned short* __restrict__ Bt,
                                          int m0, int n0, int K,
                                          char* a_lds, char* b_lds,  // each 2 x 16KB
                                          f32x4 (&acc)[4][4]) {
  const int tid = threadIdx.x;
  const int w = tid >> 6, l = tid & 63;
  const int wr = w >> 1, wc = w & 1;
  const int c = l & 15, g = l >> 4;

  const size_t rs = (size_t)K * 2;  // row stride bytes
  const int lr = l >> 3;
  const int jsw = ((l & 7) ^ lr) << 4;  // pre-swizzled source granule
  const char* srcA = (const char*)A + ((size_t)m0 + w * 8 + lr) * rs + jsw;
  const char* srcB = (const char*)Bt + ((size_t)n0 + w * 8 + lr) * rs + jsw;
  char* dstA = a_lds + w * 1024 + l * 16;
  char* dstB = b_lds + w * 1024 + l * 16;
  const int csw = (c & 7) << 4;
  const int nsteps = K / 64;

  auto stage = [&](int buf, int kt) {
    const int off = buf * 16384;
#pragma unroll
    for (int i = 0; i < 4; ++i) {
      async_copy16(srcA + (size_t)i * 32 * rs + kt * 128, dstA + off + i * 4096);
      async_copy16(srcB + (size_t)i * 32 * rs + kt * 128, dstB + off + i * 4096);
    }
  };

  stage(0, 0);
  asm volatile("s_waitcnt vmcnt(0)" ::: "memory");
  __syncthreads();
  int cur = 0;

  for (int kt = 0; kt < nsteps; ++kt) {
    if (kt + 1 < nsteps) stage(cur ^ 1, kt + 1);  // issue next tile early
    const char* al = a_lds + cur * 16384;
    const char* bl = b_lds + cur * 16384;
    __builtin_amdgcn_s_setprio(1);
#pragma unroll
    for (int kk = 0; kk < 2; ++kk) {
      bf16x8 af[4], bfv[4];
#pragma unroll
      for (int mi = 0; mi < 4; ++mi)
        af[mi] = *(const bf16x8*)(al + (wr * 64 + mi * 16 + c) * 128 + ((kk * 64 + g * 16) ^ csw));
#pragma unroll
      for (int ni = 0; ni < 4; ++ni)
        bfv[ni] = *(const bf16x8*)(bl + (wc * 64 + ni * 16 + c) * 128 + ((kk * 64 + g * 16) ^ csw));
#pragma unroll
      for (int mi = 0; mi < 4; ++mi)
#pragma unroll
        for (int ni = 0; ni < 4; ++ni)
          acc[mi][ni] = __builtin_amdgcn_mfma_f32_16x16x32_bf16(af[mi], bfv[ni], acc[mi][ni], 0, 0, 0);
    }
    __builtin_amdgcn_s_setprio(0);
    asm volatile("s_waitcnt vmcnt(0)" ::: "memory");  // next tile landed
    __syncthreads();                                  // all waves done with cur
    cur ^= 1;
  }
}

// ---------------- QKV projection + fused RoPE: q,k -> [b,h,s,d]; v -> [b,h,d,s] ----------------
__global__ __launch_bounds__(256)
void gemm_qkv_kernel(const unsigned short* __restrict__ X,
                     const unsigned short* __restrict__ Wq,
                     const unsigned short* __restrict__ Wk,
                     const unsigned short* __restrict__ Wv,
                     const float2* __restrict__ tab,
                     unsigned short* __restrict__ Qb,
                     unsigned short* __restrict__ Kb,
                     unsigned short* __restrict__ Vt) {
  __shared__ char a_lds[2 * 16384];
  __shared__ char b_lds[2 * 16384];
  const int z = blockIdx.z;
  const unsigned short* Bt = (z == 0) ? Wq : (z == 1) ? Wk : Wv;
  const int m0 = blockIdx.x * 128, n0 = blockIdx.y * 128;

  f32x4 acc[4][4] = {};
  gemm_core(X, Bt, m0, n0, DM, a_lds, b_lds, acc);

  const int tid = threadIdx.x;
  const int w = tid >> 6, l = tid & 63;
  const int wr = w >> 1, wc = w & 1;
  const int c = l & 15, g = l >> 4;

  if (z == 2) {
#pragma unroll
    for (int mi = 0; mi < 4; ++mi)
#pragma unroll
      for (int ni = 0; ni < 4; ++ni)
#pragma unroll
        for (int r = 0; r < 4; ++r) {
          int row = m0 + wr * 64 + mi * 16 + 4 * g + r;  // token
          int col = n0 + wc * 64 + ni * 16 + c;          // feature
          int b = row >> 11, s = row & 2047;
          int h = col >> 6, d = col & 63;
          Vt[((size_t)(b * NH + h) * HD + d) * S_LEN + s] = f2bf(acc[mi][ni][r]);
        }
  } else {
    unsigned short* QK = z ? Kb : Qb;
    const float oscale = z ? 1.0f : QSCALE;
#pragma unroll
    for (int mi = 0; mi < 4; ++mi)
#pragma unroll
      for (int ni = 0; ni < 4; ++ni) {
        int col = n0 + wc * 64 + ni * 16 + c;
        int fi = (col >> 1) & 31;
        float sgn = (col & 1) ? 1.0f : -1.0f;
#pragma unroll
        for (int r = 0; r < 4; ++r) {
          int row = m0 + wr * 64 + mi * 16 + 4 * g + r;
          int b = row >> 11, s = row & 2047;
          float v = acc[mi][ni][r];
          float p = __shfl_xor(v, 1);
          float2 csn = tab[(s << 5) | fi];
          float vr = (v * csn.x + sgn * p * csn.y) * oscale;
          int h = col >> 6, d = col & 63;
          QK[((size_t)(b * NH + h) * S_LEN + s) * HD + d] = f2bf(vr);
        }
      }
  }
}

// ---------------- output projection: fp32 out ----------------
__global__ __launch_bounds__(256)
void gemm_out_kernel(const unsigned short* __restrict__ A,
                     const unsigned short* __restrict__ Wo,
                     float* __restrict__ out) {
  __shared__ char a_lds[2 * 16384];
  __shared__ char b_lds[2 * 16384];
  const int m0 = blockIdx.x * 128, n0 = blockIdx.y * 128;
  f32x4 acc[4][4] = {};
  gemm_core(A, Wo, m0, n0, DM, a_lds, b_lds, acc);

  const int tid = threadIdx.x;
  const int w = tid >> 6, l = tid & 63;
  const int wr = w >> 1, wc = w & 1;
  const int c = l & 15, g = l >> 4;
#pragma unroll
  for (int mi = 0; mi < 4; ++mi)
#pragma unroll
    for (int ni = 0; ni < 4; ++ni)
#pragma unroll
      for (int r = 0; r < 4; ++r) {
        int row = m0 + wr * 64 + mi * 16 + 4 * g + r;
        int col = n0 + wc * 64 + ni * 16 + c;
        out[(size_t)row * DM + col] = acc[mi][ni][r];
      }
}

// ---------------- causal flash attention: in-block kv-parity split, 8 waves, LDS combine ----------
// Block (bh, j): 33 (qtile, kvtile) pairs of {qa=j, qb=31-j} dealt alternately to 2 wave-groups
// (G = w>>2). Each group: 4 waves (ws strips), private double-buffered K/V LDS, 17/16 uniform steps.
// Partials for qa/qb in registers; final combine via LDS (3 barriers). 4 waves/SIMD occupancy.
__global__ __launch_bounds__(512, 4)
void attn_kernel(const unsigned short* __restrict__ Q,
                 const unsigned short* __restrict__ Kb,
                 const unsigned short* __restrict__ Vt,
                 unsigned short* __restrict__ Ob) {
  __shared__ char kbuf[2][2][8192];  // [group][buf]
  __shared__ char vbuf[2][2][8192];
  const int tid = threadIdx.x;
  const int w = tid >> 6, l = tid & 63;
  const int G = w >> 2, ws = w & 3;
  const int g = l >> 4, c = l & 15;

  const unsigned int id = blockIdx.x;
  const int bh = id & 31;
  const int j = id >> 5;  // 0..15
  const int qa = j, qb = 31 - j;
  const int q0a = qa * 64, q0b = qb * 64;

  const size_t base = (size_t)bh * (S_LEN * HD);
  const char* Kc = (const char*)(Kb + base);
  const char* Vc = (const char*)(Vt + base);

  const int lr = l >> 3;
  const int jsw = ((l & 7) << 4) ^ (lr << 4);
  const int rr0 = ws * 8 + lr;
  const int rr1 = (4 + ws) * 8 + lr;
  const char* ksrc0 = Kc + rr0 * 128 + jsw;
  const char* ksrc1 = Kc + rr1 * 128 + jsw;
  const char* vsrc0 = Vc + rr0 * 4096 + jsw;
  const char* vsrc1 = Vc + rr1 * 4096 + jsw;

  bf16x8 qfA0, qfA1, qfB0, qfB1;
  {
    const unsigned short* qpA = Q + base + (size_t)(q0a + ws * 16 + c) * HD + g * 8;
    qfA0 = *(const bf16x8*)qpA;
    qfA1 = *(const bf16x8*)(qpA + 32);
    const unsigned short* qpB = Q + base + (size_t)(q0b + ws * 16 + c) * HD + g * 8;
    qfB0 = *(const bf16x8*)qpB;
    qfB1 = *(const bf16x8*)(qpB + 32);
  }
  f32x4 oaccA[4] = {}, oaccB[4] = {};
  float rsA = 0.f, rsB = 0.f;
  const int csw = (c & 7) << 4;
  const int srcA = (l & 15) | ((l & 16) << 1);
  const int srcB = srcA + 16;
  const bool hi = (l >= 32);

  auto stage = [&](int buf, int t) {
    char* kd = &kbuf[G][buf][ws * 1024 + l * 16];
    char* vd = &vbuf[G][buf][ws * 1024 + l * 16];
    size_t ko = (size_t)t * 8192;
    size_t vo = (size_t)t * 128;
    async_copy16(ksrc0 + ko, kd);
    async_copy16(ksrc1 + ko, kd + 4096);
    async_copy16(vsrc0 + vo, vd);
    async_copy16(vsrc1 + vo, vd + 4096);
  };

  // step body: one (q0/qcur, t) pair against K/V tile in (kl, vl)
  auto body = [&](const char* kl, const char* vl, int q0, int qcur, int t,
                  bf16x8 q0f, bf16x8 q1f, f32x4(&oacc)[4], float& rsum) {
    const int kv0 = t * 64;
    f32x4 sc[4] = {};
    __builtin_amdgcn_s_setprio(1);
#pragma unroll
    for (int nt = 0; nt < 4; ++nt) {
      bf16x8 k0 = *(const bf16x8*)(kl + (nt * 16 + c) * 128 + ((g * 16) ^ csw));
      bf16x8 k1 = *(const bf16x8*)(kl + (nt * 16 + c) * 128 + ((64 + g * 16) ^ csw));
      sc[nt] = __builtin_amdgcn_mfma_f32_16x16x32_bf16(k0, q0f, sc[nt], 0, 0, 0);
      sc[nt] = __builtin_amdgcn_mfma_f32_16x16x32_bf16(k1, q1f, sc[nt], 0, 0, 0);
    }
    __builtin_amdgcn_s_setprio(0);
    if (t == qcur) {
      const int qi = q0 + ws * 16 + c;
#pragma unroll
      for (int nt = 0; nt < 4; ++nt)
#pragma unroll
        for (int r = 0; r < 4; ++r) {
          int kvi = kv0 + nt * 16 + 4 * g + r;
          sc[nt][r] = exp2f((kvi > qi) ? -1e30f : sc[nt][r]);
        }
    } else {
#pragma unroll
      for (int nt = 0; nt < 4; ++nt)
#pragma unroll
        for (int r = 0; r < 4; ++r)
          sc[nt][r] = exp2f(sc[nt][r]);
    }
    unsigned int pk[4][2];
#pragma unroll
    for (int nt = 0; nt < 4; ++nt) {
      rsum += (sc[nt][0] + sc[nt][1]) + (sc[nt][2] + sc[nt][3]);
      pk[nt][0] = cvt_pk_bf16(sc[nt][0], sc[nt][1]);
      pk[nt][1] = cvt_pk_bf16(sc[nt][2], sc[nt][3]);
    }
    __builtin_amdgcn_s_setprio(1);
#pragma unroll
    for (int ks = 0; ks < 2; ++ks) {
      int a0 = __shfl((int)pk[2 * ks][0], srcA);
      int a1 = __shfl((int)pk[2 * ks][1], srcA);
      int a2 = __shfl((int)pk[2 * ks][0], srcB);
      int a3 = __shfl((int)pk[2 * ks][1], srcB);
      int b0 = __shfl((int)pk[2 * ks + 1][0], srcA);
      int b1 = __shfl((int)pk[2 * ks + 1][1], srcA);
      int b2 = __shfl((int)pk[2 * ks + 1][0], srcB);
      int b3 = __shfl((int)pk[2 * ks + 1][1], srcB);
      i32x4 pw;
      pw[0] = hi ? b0 : a0;
      pw[1] = hi ? b1 : a1;
      pw[2] = hi ? b2 : a2;
      pw[3] = hi ? b3 : a3;
      bf16x8 pf = __builtin_bit_cast(bf16x8, pw);
#pragma unroll
      for (int nt = 0; nt < 4; ++nt) {
        bf16x8 vf = *(const bf16x8*)(vl + (nt * 16 + c) * 128 + ((ks * 64 + g * 16) ^ csw));
        oacc[nt] = __builtin_amdgcn_mfma_f32_16x16x32_bf16(vf, pf, oacc[nt], 0, 0, 0);
      }
    }
    __builtin_amdgcn_s_setprio(0);
  };

  {
    int t0 = (G <= qa) ? G : G - qa - 1;  // pair index i = G
    stage(0, t0);
  }
  asm volatile("s_waitcnt vmcnt(0)" ::: "memory");
  __syncthreads();
  int cur = 0;

  for (int s = 0; s < 17; ++s) {
    const int i = 2 * s + G;
    const int inext = i + 2;
    if (inext <= 32) {
      int tn = (inext <= qa) ? inext : inext - qa - 1;
      stage(cur ^ 1, tn);
    }
    if (i <= 32) {
      const char* kl = kbuf[G][cur];
      const char* vl = vbuf[G][cur];
      if (i <= qa)
        body(kl, vl, q0a, qa, i, qfA0, qfA1, oaccA, rsA);
      else
        body(kl, vl, q0b, qb, i - qa - 1, qfB0, qfB1, oaccB, rsB);
    }
    asm volatile("s_waitcnt vmcnt(0)" ::: "memory");
    __syncthreads();
    cur ^= 1;
  }

  // -------- intra-block combine (parity partials) --------
  rsA += __shfl_xor(rsA, 16);
  rsA += __shfl_xor(rsA, 32);
  rsB += __shfl_xor(rsB, 16);
  rsB += __shfl_xor(rsB, 32);
  float* lf = (float*)&kbuf[0][0][0];   // 64x64 fp32 = 16KB
  float* lrs = (float*)&vbuf[0][0][0];  // 64 fp32
  const int row = ws * 16 + c;
  const int b = bh >> 4, h = bh & 15;

  // Round A: group1 writes qa-partial; group0 finalizes qa
  if (G == 1) {
#pragma unroll
    for (int nt = 0; nt < 4; ++nt)
      *(f32x4*)(lf + row * 64 + nt * 16 + 4 * g) = oaccA[nt];
    if (g == 0) lrs[row] = rsA;
  }
  __syncthreads();
  if (G == 0) {
    float inv = 1.0f / (rsA + lrs[row]);
    unsigned short* dst = Ob + ((size_t)b * S_LEN + q0a + row) * DM + h * HD + 4 * g;
#pragma unroll
    for (int nt = 0; nt < 4; ++nt) {
      f32x4 o = oaccA[nt] + *(f32x4*)(lf + row * 64 + nt * 16 + 4 * g);
      unsigned int w0 = (unsigned int)f2bf(o[0] * inv) | ((unsigned int)f2bf(o[1] * inv) << 16);
      unsigned int w1 = (unsigned int)f2bf(o[2] * inv) | ((unsigned int)f2bf(o[3] * inv) << 16);
      uint2 pr;
      pr.x = w0;
      pr.y = w1;
      *(uint2*)(dst + nt * 16) = pr;
    }
  }
  __syncthreads();
  // Round B: group0 writes qb-partial; group1 finalizes qb
  if (G == 0) {
#pragma unroll
    for (int nt = 0; nt < 4; ++nt)
      *(f32x4*)(lf + row * 64 + nt * 16 + 4 * g) = oaccB[nt];
    if (g == 0) lrs[row] = rsB;
  }
  __syncthreads();
  if (G == 1) {
    float inv = 1.0f / (rsB + lrs[row]);
    unsigned short* dst = Ob + ((size_t)b * S_LEN + q0b + row) * DM + h * HD + 4 * g;
#pragma unroll
    for (int nt = 0; nt < 4; ++nt) {
      f32x4 o = oaccB[nt] + *(f32x4*)(lf + row * 64 + nt * 16 + 4 * g);
      unsigned int w0 = (unsigned int)f2bf(o[0] * inv) | ((unsigned int)f2bf(o[1] * inv) << 16);
      unsigned int w1 = (unsigned int)f2bf(o[2] * inv) | ((unsigned int)f2bf(o[3] * inv) << 16);
      uint2 pr;
      pr.x = w0;
      pr.y = w1;
      *(uint2*)(dst + nt * 16) = pr;
    }
  }
}

extern "C" void kernel_launch(void* const* d_in, const int* in_sizes, int n_in,
                              void* d_out, int out_size, void* d_ws, size_t ws_size,
                              hipStream_t stream) {
  const float* x = (const float*)d_in[0];
  const int* tpos = (const int*)d_in[1];
  const float* wq = (const float*)d_in[2];
  const float* wk = (const float*)d_in[3];
  const float* wv = (const float*)d_in[4];
  const float* wo = (const float*)d_in[5];
  float* out = (float*)d_out;

  char* ws = (char*)d_ws;
  unsigned short* xb = (unsigned short*)(ws);                          // 4096x1024 bf16
  unsigned short* wqb = (unsigned short*)(ws + 8388608);               // 4x 1024x1024
  unsigned short* wkb = wqb + DM * DM;
  unsigned short* wvb = wqb + 2 * DM * DM;
  unsigned short* wob = wqb + 3 * DM * DM;
  unsigned short* qb = (unsigned short*)(ws + 16777216);               // [b,h,s,d] pre-scaled
  unsigned short* kb = (unsigned short*)(ws + 16777216 + 8388608);     // [b,h,s,d]
  unsigned short* vt = (unsigned short*)(ws + 16777216 + 2 * 8388608); // [b,h,d,s]
  unsigned short* ab = (unsigned short*)(ws + 16777216 + 3 * 8388608); // [t, h*d]
  float2* tab = (float2*)(ws + 50331648);                              // [2048][32] cos/sin

  cvt_bf16_kernel<<<2048, 256, 0, stream>>>(x, xb, MTOT * DM);
  cvt_w_kernel<<<dim3(512, 4), 256, 0, stream>>>(wq, wk, wv, wo, wqb);
  sincos_tab_kernel<<<256, 256, 0, stream>>>(tpos, tab);

  gemm_qkv_kernel<<<dim3(32, 8, 3), 256, 0, stream>>>(xb, wqb, wkb, wvb, tab, qb, kb, vt);
  attn_kernel<<<512, 512, 0, stream>>>(qb, kb, vt, ab);
  gemm_out_kernel<<<dim3(32, 8), 256, 0, stream>>>(ab, wob, out);
}